// Round 2
// baseline (821.084 us; speedup 1.0000x reference)
//
#include <hip/hip_runtime.h>

#define B_    4
#define H_    16
#define S_    2048
#define D_    64
#define SCALE 0.125f
#define PPAD  68   // 64 + 4 fp32 pad

typedef __bf16 bf16x8 __attribute__((ext_vector_type(8)));
typedef float  f32x4  __attribute__((ext_vector_type(4)));

// ---------- prepass: K fp32 -> bf16, same [bh][s][d] layout ----------
__global__ __launch_bounds__(256)
void prep_k(const float* __restrict__ K, __bf16* __restrict__ Kb) {
    size_t i = (size_t)blockIdx.x * 256 + threadIdx.x;   // 8 elems per thread
    const float4* src = reinterpret_cast<const float4*>(K) + i * 2;
    float4 a = src[0], b = src[1];
    bf16x8 w = { (__bf16)a.x,(__bf16)a.y,(__bf16)a.z,(__bf16)a.w,
                 (__bf16)b.x,(__bf16)b.y,(__bf16)b.z,(__bf16)b.w };
    reinterpret_cast<bf16x8*>(Kb)[i] = w;
}

// ---------- prepass: V fp32 [bh][s][d] -> bf16 transposed [bh][d][s] ----------
__global__ __launch_bounds__(256)
void prep_v(const float* __restrict__ V, __bf16* __restrict__ Vt) {
    __shared__ float Ls[64][65];   // odd pad: conflict-light scalar access
    const int tid = threadIdx.x;
    const int bh = blockIdx.x >> 5, st = blockIdx.x & 31;
    const float* Vp = V + ((size_t)bh * S_ + st * 64) * D_;
    for (int i = tid; i < 1024; i += 256) {           // 64x64 fp32 tile
        int r = i >> 4, c = (i & 15) << 2;
        float4 v = reinterpret_cast<const float4*>(Vp)[i];
        Ls[r][c] = v.x; Ls[r][c+1] = v.y; Ls[r][c+2] = v.z; Ls[r][c+3] = v.w;
    }
    __syncthreads();
    const int d = tid >> 2, sc = (tid & 3) * 16;
    __bf16* dst = Vt + ((size_t)bh * D_ + d) * S_ + st * 64 + sc;
    bf16x8 w0, w1;
    #pragma unroll
    for (int j = 0; j < 8; ++j) w0[j] = (__bf16)Ls[sc + j][d];
    #pragma unroll
    for (int j = 0; j < 8; ++j) w1[j] = (__bf16)Ls[sc + 8 + j][d];
    *reinterpret_cast<bf16x8*>(dst)     = w0;
    *reinterpret_cast<bf16x8*>(dst + 8) = w1;
}

// ---------- main: barrier-free after prologue ----------
__global__ __launch_bounds__(256, 4)
void sdpa_main(const float* __restrict__ Q, const __bf16* __restrict__ Kb,
               const __bf16* __restrict__ Vt, const int* __restrict__ mask,
               float* __restrict__ ctx_out, float* __restrict__ attn_out)
{
    __shared__ float Ps[4][16][PPAD];   // wave-private P strips (transpose bounce)

    const int tid  = threadIdx.x;
    const int lane = tid & 63, wid = tid >> 6;
    const int l15  = lane & 15, lhi = lane >> 4;
    const int kbase = lhi * 8;

    // XCD swizzle: all 32 q-blocks of a bh land on one XCD (K+V bf16 = 512KB in its L2)
    const int orig = blockIdx.x, cpx = gridDim.x >> 3;
    const int bid  = (orig & 7) * cpx + (orig >> 3);
    const int qt = bid & 31, bh = bid >> 5, b = bh >> 4;

    const __bf16* Kp = Kb + (size_t)bh * S_ * D_;
    const __bf16* Vp = Vt + (size_t)bh * D_ * S_;
    const int*    mp = mask + b * S_;

    // Q A-fragments straight from fp32 global (prologue only)
    bf16x8 aQ[2];
    {
        const float* qrow = Q + ((size_t)bh * S_ + qt * 64 + wid * 16 + l15) * D_ + kbase;
        #pragma unroll
        for (int ks = 0; ks < 2; ++ks) {
            float4 a = *reinterpret_cast<const float4*>(qrow + ks * 32);
            float4 c = *reinterpret_cast<const float4*>(qrow + ks * 32 + 4);
            bf16x8 w = { (__bf16)a.x,(__bf16)a.y,(__bf16)a.z,(__bf16)a.w,
                         (__bf16)c.x,(__bf16)c.y,(__bf16)c.z,(__bf16)c.w };
            aQ[ks] = w;
        }
    }

    // ---------------- pass 1: row sums (no LDS, no barriers) ----------------
    float lsum[4] = {0.f, 0.f, 0.f, 0.f};
    for (int kt = 0; kt < S_ / 64; ++kt) {
        const __bf16* kb_base = Kp + (size_t)kt * 64 * D_;
        bf16x8 kf[4][2];
        int mv[4];
        #pragma unroll
        for (int sub = 0; sub < 4; ++sub) {
            const __bf16* krow = kb_base + (size_t)(sub * 16 + l15) * D_ + kbase;
            kf[sub][0] = *reinterpret_cast<const bf16x8*>(krow);
            kf[sub][1] = *reinterpret_cast<const bf16x8*>(krow + 32);
            mv[sub]    = mp[kt * 64 + sub * 16 + l15];
        }
        #pragma unroll
        for (int sub = 0; sub < 4; ++sub) {
            f32x4 acc = {0.f, 0.f, 0.f, 0.f};
            acc = __builtin_amdgcn_mfma_f32_16x16x32_bf16(aQ[0], kf[sub][0], acc, 0, 0, 0);
            acc = __builtin_amdgcn_mfma_f32_16x16x32_bf16(aQ[1], kf[sub][1], acc, 0, 0, 0);
            float flag = mv[sub] ? 0.0f : 1.0f;
            #pragma unroll
            for (int r = 0; r < 4; ++r)
                lsum[r] += flag * __expf(acc[r] * SCALE);
        }
    }
    #pragma unroll
    for (int r = 0; r < 4; ++r) {
        lsum[r] += __shfl_xor(lsum[r], 1);
        lsum[r] += __shfl_xor(lsum[r], 2);
        lsum[r] += __shfl_xor(lsum[r], 4);
        lsum[r] += __shfl_xor(lsum[r], 8);
    }
    float rl[4];
    #pragma unroll
    for (int r = 0; r < 4; ++r) rl[r] = 1.0f / lsum[r];

    // ---------------- pass 2: attn store (direct from accum) + PV ----------------
    const f32x4 vzero = {0.f, 0.f, 0.f, 0.f};
    f32x4 ctx[4];
    #pragma unroll
    for (int d = 0; d < 4; ++d) ctx[d] = vzero;

    const size_t arow0 = (size_t)bh * S_ + (size_t)qt * 64 + wid * 16;

    for (int kt = 0; kt < S_ / 64; ++kt) {
        const __bf16* kb_base = Kp + (size_t)kt * 64 * D_;
        bf16x8 kf[4][2];
        int mv[4];
        #pragma unroll
        for (int sub = 0; sub < 4; ++sub) {
            const __bf16* krow = kb_base + (size_t)(sub * 16 + l15) * D_ + kbase;
            kf[sub][0] = *reinterpret_cast<const bf16x8*>(krow);
            kf[sub][1] = *reinterpret_cast<const bf16x8*>(krow + 32);
            mv[sub]    = mp[kt * 64 + sub * 16 + l15];
        }
        #pragma unroll
        for (int sub = 0; sub < 4; ++sub) {
            f32x4 acc = {0.f, 0.f, 0.f, 0.f};
            acc = __builtin_amdgcn_mfma_f32_16x16x32_bf16(aQ[0], kf[sub][0], acc, 0, 0, 0);
            acc = __builtin_amdgcn_mfma_f32_16x16x32_bf16(aQ[1], kf[sub][1], acc, 0, 0, 0);
            float flag = mv[sub] ? 0.0f : 1.0f;
            #pragma unroll
            for (int r = 0; r < 4; ++r) {
                float p = flag * __expf(acc[r] * SCALE) * rl[r];
                // direct store: lanes l15 = 16 consecutive fp32 -> full 64B lines
                attn_out[(arow0 + lhi * 4 + r) * S_ + kt * 64 + sub * 16 + l15] = p;
                Ps[wid][lhi * 4 + r][sub * 16 + l15] = p;
            }
        }
        // P transpose via wave-private LDS (same-wave ordering, no barrier)
        bf16x8 aP[2];
        #pragma unroll
        for (int ks = 0; ks < 2; ++ks) {
            const float* src = &Ps[wid][l15][ks * 32 + kbase];
            f32x4 lo = *reinterpret_cast<const f32x4*>(src);
            f32x4 hi = *reinterpret_cast<const f32x4*>(src + 4);
            bf16x8 t;
            t[0] = (__bf16)lo[0]; t[1] = (__bf16)lo[1];
            t[2] = (__bf16)lo[2]; t[3] = (__bf16)lo[3];
            t[4] = (__bf16)hi[0]; t[5] = (__bf16)hi[1];
            t[6] = (__bf16)hi[2]; t[7] = (__bf16)hi[3];
            aP[ks] = t;
        }
        #pragma unroll
        for (int dblk = 0; dblk < 4; ++dblk) {
            const __bf16* vrow = Vp + (size_t)(dblk * 16 + l15) * S_ + kt * 64 + kbase;
            bf16x8 v0 = *reinterpret_cast<const bf16x8*>(vrow);
            bf16x8 v1 = *reinterpret_cast<const bf16x8*>(vrow + 32);
            ctx[dblk] = __builtin_amdgcn_mfma_f32_16x16x32_bf16(aP[0], v0, ctx[dblk], 0, 0, 0);
            ctx[dblk] = __builtin_amdgcn_mfma_f32_16x16x32_bf16(aP[1], v1, ctx[dblk], 0, 0, 0);
        }
    }

    // context write: row = lhi*4+r, col = dblk*16+l15
    #pragma unroll
    for (int dblk = 0; dblk < 4; ++dblk) {
        #pragma unroll
        for (int r = 0; r < 4; ++r) {
            ctx_out[(arow0 + lhi * 4 + r) * D_ + dblk * 16 + l15] = ctx[dblk][r];
        }
    }
}

extern "C" void kernel_launch(void* const* d_in, const int* in_sizes, int n_in,
                              void* d_out, int out_size, void* d_ws, size_t ws_size,
                              hipStream_t stream) {
    const float* Q    = (const float*)d_in[0];
    const float* K    = (const float*)d_in[1];
    const float* V    = (const float*)d_in[2];
    const int*   mask = (const int*)d_in[3];

    float* ctx_out  = (float*)d_out;
    float* attn_out = ctx_out + (size_t)B_ * H_ * S_ * D_;

    // workspace: bf16 K (16.8 MB) + bf16 V^T (16.8 MB)
    __bf16* Kb = (__bf16*)d_ws;
    __bf16* Vt = Kb + (size_t)B_ * H_ * S_ * D_;

    const int elems = B_ * H_ * S_ * D_;                 // 8.4M
    prep_k<<<elems / (256 * 8), 256, 0, stream>>>(K, Kb);
    prep_v<<<B_ * H_ * (S_ / 64), 256, 0, stream>>>(V, Vt);
    sdpa_main<<<B_ * H_ * (S_ / 64), 256, 0, stream>>>(Q, Kb, Vt, mask, ctx_out, attn_out);
}

// Round 3
// 405.600 us; speedup vs baseline: 2.0244x; 2.0244x over previous
//
#include <hip/hip_runtime.h>
#include <stdint.h>

#define B_    4
#define H_    16
#define S_    2048
#define D_    64
#define SCALE_LOG2E 0.1803368801111244f   // 0.125 * log2(e)

typedef __bf16 bf16x8 __attribute__((ext_vector_type(8)));
typedef float  f32x4  __attribute__((ext_vector_type(4)));

// ---- prepass: K fp32 [bh][s][d] -> swizzled bf16 tile image [bh*32+kt][8192B]
// image byte L (row = L>>7, cb = L&127) holds element (row, cb ^ ((row&7)<<4))
__global__ __launch_bounds__(256)
void prep_k(const float* __restrict__ K, __bf16* __restrict__ img) {
    int t    = blockIdx.x * 256 + threadIdx.x;   // 1,048,576 threads, 16B each
    int tile = t >> 9;
    int L    = (t & 511) << 4;
    int row  = L >> 7;
    int cb   = L & 127;
    int scb  = cb ^ ((row & 7) << 4);            // source column byte
    int bh = tile >> 5, kt = tile & 31;
    const float* src = K + (((size_t)bh * S_ + kt * 64 + row) * D_ + (scb >> 1));
    float4 a = *reinterpret_cast<const float4*>(src);
    float4 b = *reinterpret_cast<const float4*>(src + 4);
    bf16x8 w = { (__bf16)a.x,(__bf16)a.y,(__bf16)a.z,(__bf16)a.w,
                 (__bf16)b.x,(__bf16)b.y,(__bf16)b.z,(__bf16)b.w };
    *reinterpret_cast<bf16x8*>((char*)img + ((size_t)t << 4)) = w;
}

// ---- prepass: V fp32 [bh][s][d] -> swizzled bf16 transposed tile image (rows = d)
__global__ __launch_bounds__(256)
void prep_v(const float* __restrict__ V, __bf16* __restrict__ img) {
    __shared__ float Ls[64][65];
    const int tid = threadIdx.x;
    const int bh = blockIdx.x >> 5, st = blockIdx.x & 31;
    const float* Vp = V + ((size_t)bh * S_ + st * 64) * D_;
    for (int i = tid; i < 1024; i += 256) {
        int r = i >> 4, c = (i & 15) << 2;
        float4 v = reinterpret_cast<const float4*>(Vp)[i];
        Ls[r][c] = v.x; Ls[r][c+1] = v.y; Ls[r][c+2] = v.z; Ls[r][c+3] = v.w;
    }
    __syncthreads();
    const int d = tid >> 2, sc = (tid & 3) * 16;
    bf16x8 w0, w1;
    #pragma unroll
    for (int j = 0; j < 8; ++j) w0[j] = (__bf16)Ls[sc + j][d];
    #pragma unroll
    for (int j = 0; j < 8; ++j) w1[j] = (__bf16)Ls[sc + 8 + j][d];
    char* tb = (char*)img + (size_t)(bh * 32 + st) * 8192;
    int sw = (d & 7) << 4;
    *reinterpret_cast<bf16x8*>(tb + d * 128 + ((sc * 2) ^ sw))      = w0;
    *reinterpret_cast<bf16x8*>(tb + d * 128 + ((sc * 2 + 16) ^ sw)) = w1;
}

__device__ __forceinline__ void gload16(const void* g, void* l) {
    __builtin_amdgcn_global_load_lds(
        (const __attribute__((address_space(1))) void*)g,
        (__attribute__((address_space(3))) void*)l, 16, 0, 0);
}

__global__ __launch_bounds__(256, 3)
void sdpa_main(const float* __restrict__ Q, const __bf16* __restrict__ Kimg,
               const __bf16* __restrict__ Vimg, const int* __restrict__ mask,
               float* __restrict__ ctx_out, float* __restrict__ attn_out)
{
    __shared__ __align__(16) __bf16 Kb[2][4096];   // 2 x 8KB
    __shared__ __align__(16) __bf16 Vb[2][4096];   // 2 x 8KB
    __shared__ __align__(16) float  Ps[4][16][68]; // 17KB (also prologue scratch)

    const int tid = threadIdx.x;
    const int lane = tid & 63, wid = tid >> 6;
    const int l15 = lane & 15, lhi = lane >> 4;

    const int orig = blockIdx.x, cpx = gridDim.x >> 3;
    const int bid = (orig & 7) * cpx + (orig >> 3);
    const int qt = bid & 31, bh = bid >> 5, b = bh >> 4;

    const char* KimgT = (const char*)Kimg + (size_t)bh * 32 * 8192;
    const char* VimgT = (const char*)Vimg + (size_t)bh * 32 * 8192;
    const int*  mp = mask + b * S_;

    // ---------------- prologue ----------------
    float* msc = &Ps[0][0][0];                    // 2048 floats scratch
    for (int i = tid; i < S_; i += 256) msc[i] = mp[i] ? 1.f : 0.f;

    {   // stage K tile e(0) = qt into Kb[0]
        const char* src = KimgT + qt * 8192 + wid * 2048 + lane * 16;
        char* dst = (char*)&Kb[0][0] + wid * 2048;
        gload16(src,        dst);
        gload16(src + 1024, dst + 1024);
    }

    bf16x8 aQ0, aQ1;
    {   // Q fragments (row = wid*16+l15, k = ks*32 + lhi*8 + j)
        const float* qrow = Q + ((size_t)bh * S_ + qt * 64 + wid * 16 + l15) * D_ + lhi * 8;
        float4 a = *reinterpret_cast<const float4*>(qrow);
        float4 c = *reinterpret_cast<const float4*>(qrow + 4);
        bf16x8 w0 = { (__bf16)a.x,(__bf16)a.y,(__bf16)a.z,(__bf16)a.w,
                      (__bf16)c.x,(__bf16)c.y,(__bf16)c.z,(__bf16)c.w };
        aQ0 = w0;
        a = *reinterpret_cast<const float4*>(qrow + 32);
        c = *reinterpret_cast<const float4*>(qrow + 36);
        bf16x8 w1 = { (__bf16)a.x,(__bf16)a.y,(__bf16)a.z,(__bf16)a.w,
                      (__bf16)c.x,(__bf16)c.y,(__bf16)c.z,(__bf16)c.w };
        aQ1 = w1;
    }

    __syncthreads();   // msc visible to all; stage of Kb[0] drained

    // pack mask bits: tile e -> word e>>3, bit (e&7)*4 + sub  (bit set = masked)
    uint32_t m0 = 0, m1 = 0, m2 = 0, m3 = 0;
    #pragma unroll
    for (int kk = 0; kk < 8; ++kk) {
        #pragma unroll
        for (int sub = 0; sub < 4; ++sub) {
            int bit = kk * 4 + sub;
            if (msc[(kk     ) * 64 + sub * 16 + l15] != 0.f) m0 |= 1u << bit;
            if (msc[(kk +  8) * 64 + sub * 16 + l15] != 0.f) m1 |= 1u << bit;
            if (msc[(kk + 16) * 64 + sub * 16 + l15] != 0.f) m2 |= 1u << bit;
            if (msc[(kk + 24) * 64 + sub * 16 + l15] != 0.f) m3 |= 1u << bit;
        }
    }

    // per-lane swizzled LDS frag byte offsets (identical for K and V tiles)
    int fo[4][2];
    #pragma unroll
    for (int sub = 0; sub < 4; ++sub) {
        int row = sub * 16 + l15;
        int sw = (row & 7) << 4;
        fo[sub][0] = row * 128 + ((lhi * 16) ^ sw);
        fo[sub][1] = row * 128 + ((64 + lhi * 16) ^ sw);
    }

    // ---------------- pass 1: row sums ----------------
    float ls[4] = {0.f, 0.f, 0.f, 0.f};
    int cur = 0;
    for (int kt = 0; kt < 32; ++kt) {
        int e  = (kt + qt) & 31;
        int en = (kt + 1 + qt) & 31;
        {   // stage next K
            const char* src = KimgT + en * 8192 + wid * 2048 + lane * 16;
            char* dst = (char*)&Kb[cur ^ 1][0] + wid * 2048;
            gload16(src, dst); gload16(src + 1024, dst + 1024);
        }
        const char* kb = (const char*)&Kb[cur][0];
        uint32_t mw = (e & 16) ? ((e & 8) ? m3 : m2) : ((e & 8) ? m1 : m0);
        int mbase = (e & 7) * 4;
        #pragma unroll
        for (int sub = 0; sub < 4; ++sub) {
            bf16x8 b0 = *reinterpret_cast<const bf16x8*>(kb + fo[sub][0]);
            bf16x8 b1 = *reinterpret_cast<const bf16x8*>(kb + fo[sub][1]);
            f32x4 acc = {0.f, 0.f, 0.f, 0.f};
            acc = __builtin_amdgcn_mfma_f32_16x16x32_bf16(aQ0, b0, acc, 0, 0, 0);
            acc = __builtin_amdgcn_mfma_f32_16x16x32_bf16(aQ1, b1, acc, 0, 0, 0);
            float flag = ((mw >> (mbase + sub)) & 1) ? 0.f : 1.f;
            #pragma unroll
            for (int r = 0; r < 4; ++r)
                ls[r] += flag * exp2f(acc[r] * SCALE_LOG2E);
        }
        asm volatile("s_waitcnt vmcnt(0)" ::: "memory");
        __builtin_amdgcn_s_barrier();
        cur ^= 1;
    }
    float rl[4];
    #pragma unroll
    for (int r = 0; r < 4; ++r) {
        ls[r] += __shfl_xor(ls[r], 1);
        ls[r] += __shfl_xor(ls[r], 2);
        ls[r] += __shfl_xor(ls[r], 4);
        ls[r] += __shfl_xor(ls[r], 8);
        rl[r] = 1.0f / ls[r];
    }

    // ---------------- pass 2 ----------------
    {   // stage V tile e(0) into Vb[cur]  (Kb[cur] already holds e(0) from pass 1)
        const char* src = VimgT + qt * 8192 + wid * 2048 + lane * 16;
        char* dst = (char*)&Vb[cur][0] + wid * 2048;
        gload16(src, dst); gload16(src + 1024, dst + 1024);
    }
    asm volatile("s_waitcnt vmcnt(0)" ::: "memory");
    __builtin_amdgcn_s_barrier();

    f32x4 ctx[4];
    #pragma unroll
    for (int d = 0; d < 4; ++d) ctx[d] = (f32x4){0.f, 0.f, 0.f, 0.f};
    const size_t arow0 = (size_t)bh * S_ + (size_t)qt * 64 + wid * 16;

    for (int kt = 0; kt < 32; ++kt) {
        int e  = (kt + qt) & 31;
        int en = (kt + 1 + qt) & 31;
        {   // stage next K + V
            const char* ks = KimgT + en * 8192 + wid * 2048 + lane * 16;
            const char* vs = VimgT + en * 8192 + wid * 2048 + lane * 16;
            char* kd = (char*)&Kb[cur ^ 1][0] + wid * 2048;
            char* vd = (char*)&Vb[cur ^ 1][0] + wid * 2048;
            gload16(ks, kd); gload16(ks + 1024, kd + 1024);
            gload16(vs, vd); gload16(vs + 1024, vd + 1024);
        }
        const char* kb = (const char*)&Kb[cur][0];
        const char* vb = (const char*)&Vb[cur][0];
        uint32_t mw = (e & 16) ? ((e & 8) ? m3 : m2) : ((e & 8) ? m1 : m0);
        int mbase = (e & 7) * 4;

        // QK^T -> normalized P -> Ps
        #pragma unroll
        for (int sub = 0; sub < 4; ++sub) {
            bf16x8 b0 = *reinterpret_cast<const bf16x8*>(kb + fo[sub][0]);
            bf16x8 b1 = *reinterpret_cast<const bf16x8*>(kb + fo[sub][1]);
            f32x4 acc = {0.f, 0.f, 0.f, 0.f};
            acc = __builtin_amdgcn_mfma_f32_16x16x32_bf16(aQ0, b0, acc, 0, 0, 0);
            acc = __builtin_amdgcn_mfma_f32_16x16x32_bf16(aQ1, b1, acc, 0, 0, 0);
            float flag = ((mw >> (mbase + sub)) & 1) ? 0.f : 1.f;
            #pragma unroll
            for (int r = 0; r < 4; ++r) {
                float p = flag * exp2f(acc[r] * SCALE_LOG2E) * rl[r];
                Ps[wid][lhi * 4 + r][sub * 16 + l15] = p;
            }
        }

        // attn store: float4, 16 rows x 64 cols
        #pragma unroll
        for (int it = 0; it < 4; ++it) {
            int idx = (it << 6) + lane;
            int r = idx >> 4, c = (idx & 15) << 2;
            float4 v = *reinterpret_cast<float4*>(&Ps[wid][r][c]);
            *reinterpret_cast<float4*>(&attn_out[(arow0 + r) * S_ + e * 64 + c]) = v;
        }

        // P transpose -> A fragments
        bf16x8 aP0, aP1;
        {
            const float* s0 = &Ps[wid][l15][lhi * 8];
            f32x4 lo = *reinterpret_cast<const f32x4*>(s0);
            f32x4 hi = *reinterpret_cast<const f32x4*>(s0 + 4);
            bf16x8 t;
            t[0]=(__bf16)lo[0]; t[1]=(__bf16)lo[1]; t[2]=(__bf16)lo[2]; t[3]=(__bf16)lo[3];
            t[4]=(__bf16)hi[0]; t[5]=(__bf16)hi[1]; t[6]=(__bf16)hi[2]; t[7]=(__bf16)hi[3];
            aP0 = t;
            const float* s1 = &Ps[wid][l15][32 + lhi * 8];
            lo = *reinterpret_cast<const f32x4*>(s1);
            hi = *reinterpret_cast<const f32x4*>(s1 + 4);
            t[0]=(__bf16)lo[0]; t[1]=(__bf16)lo[1]; t[2]=(__bf16)lo[2]; t[3]=(__bf16)lo[3];
            t[4]=(__bf16)hi[0]; t[5]=(__bf16)hi[1]; t[6]=(__bf16)hi[2]; t[7]=(__bf16)hi[3];
            aP1 = t;
        }

        // PV
        #pragma unroll
        for (int db = 0; db < 4; ++db) {
            bf16x8 v0 = *reinterpret_cast<const bf16x8*>(vb + fo[db][0]);
            bf16x8 v1 = *reinterpret_cast<const bf16x8*>(vb + fo[db][1]);
            ctx[db] = __builtin_amdgcn_mfma_f32_16x16x32_bf16(aP0, v0, ctx[db], 0, 0, 0);
            ctx[db] = __builtin_amdgcn_mfma_f32_16x16x32_bf16(aP1, v1, ctx[db], 0, 0, 0);
        }

        asm volatile("s_waitcnt vmcnt(0)" ::: "memory");
        __builtin_amdgcn_s_barrier();
        cur ^= 1;
    }

    #pragma unroll
    for (int db = 0; db < 4; ++db) {
        #pragma unroll
        for (int r = 0; r < 4; ++r) {
            ctx_out[(arow0 + lhi * 4 + r) * D_ + db * 16 + l15] = ctx[db][r];
        }
    }
}

extern "C" void kernel_launch(void* const* d_in, const int* in_sizes, int n_in,
                              void* d_out, int out_size, void* d_ws, size_t ws_size,
                              hipStream_t stream) {
    const float* Q    = (const float*)d_in[0];
    const float* K    = (const float*)d_in[1];
    const float* V    = (const float*)d_in[2];
    const int*   mask = (const int*)d_in[3];

    float* ctx_out  = (float*)d_out;
    float* attn_out = ctx_out + (size_t)B_ * H_ * S_ * D_;

    __bf16* Kimg = (__bf16*)d_ws;                              // 16.8 MB
    __bf16* Vimg = Kimg + (size_t)B_ * H_ * S_ * D_;           // 16.8 MB

    prep_k<<<4096, 256, 0, stream>>>(K, Kimg);
    prep_v<<<B_ * H_ * 32, 256, 0, stream>>>(V, Vimg);
    sdpa_main<<<B_ * H_ * 32, 256, 0, stream>>>(Q, Kimg, Vimg, mask, ctx_out, attn_out);
}